// Round 8
// baseline (279.135 us; speedup 1.0000x reference)
//
#include <hip/hip_runtime.h>

#define NN 100000
#define NE 1600000
constexpr int KDIM = 128;
constexpr int NPB = 128;                  // nodes per bucket (col>>7)
constexpr int G = (NN + NPB - 1) / NPB;   // 782 buckets
constexpr int CH = 4096;                  // edges per chunk
constexpr int NCH = (NE + CH - 1) / CH;   // 391 chunks
constexpr int CAP = 4000;                 // padded bucket capacity (mean 2046, sigma 45)

typedef _Float16 f16x4 __attribute__((ext_vector_type(4)));
typedef _Float16 f16x8 __attribute__((ext_vector_type(8)));
typedef float f32x4 __attribute__((ext_vector_type(4)));
using half8 = f16x8;

// LDS XOR swizzle for 256B-row-stride b128 access: spreads bank slots
__device__ __forceinline__ int swz(int byte) {
  return byte ^ (((byte >> 8) & 7) << 4);
}

// ---------------- preprocessing: bucketed counting sort (padded) -------------

__global__ __launch_bounds__(256) void k_zero(int* p, int n) {
  int i = blockIdx.x * 256 + threadIdx.x;
  if (i < n) p[i] = 0;
}

// bin edges into padded bucket regions: LDS hist + bulk reservation + append
__global__ __launch_bounds__(256) void k_bucketP(const int* __restrict__ row,
                                                 const int* __restrict__ col,
                                                 int* __restrict__ cursor,
                                                 unsigned long long* __restrict__ temp) {
  __shared__ int h[G];
  for (int i = threadIdx.x; i < G; i += 256) h[i] = 0;
  __syncthreads();
  const int base = blockIdx.x * CH;
  const int m = min(CH, NE - base);
  for (int i = threadIdx.x; i < m; i += 256) atomicAdd(&h[col[base + i] >> 7], 1);
  __syncthreads();
  for (int i = threadIdx.x; i < G; i += 256) {
    int c = h[i];
    if (c) h[i] = atomicAdd(&cursor[i], c);  // h[i] becomes this WG's local base
  }
  __syncthreads();
  for (int i = threadIdx.x; i < m; i += 256) {
    int cc = col[base + i];
    int rr = row[base + i];
    int slot = atomicAdd(&h[cc >> 7], 1);
    temp[(size_t)(cc >> 7) * CAP + slot] =
        ((unsigned long long)(unsigned)cc << 32) | (unsigned)rr;
  }
}

// exclusive scan of bucket counts (in cursor) -> bbase[0..G]
__global__ void k_bscan(const int* __restrict__ cnt, int* __restrict__ bbase) {
  __shared__ int sd[256];
  const int t = threadIdx.x;
  int v[4];
  int s = 0;
#pragma unroll
  for (int j = 0; j < 4; ++j) {
    int idx = t * 4 + j;
    v[j] = (idx < G) ? cnt[idx] : 0;
    s += v[j];
  }
  sd[t] = s;
  __syncthreads();
  for (int off = 1; off < 256; off <<= 1) {
    int x = (t >= off) ? sd[t - off] : 0;
    __syncthreads();
    sd[t] += x;
    __syncthreads();
  }
  int run = sd[t] - s;  // exclusive prefix
#pragma unroll
  for (int j = 0; j < 4; ++j) {
    int idx = t * 4 + j;
    if (idx < G) bbase[idx] = run;
    run += v[j];
  }
  if (t == 255) bbase[G] = run;  // == NE
}

// per-bucket: LDS node hist -> scan -> rowptr/dinv, then group srcs (CSR)
__global__ __launch_bounds__(256) void k_groupP(const unsigned long long* __restrict__ temp,
                                                const int* __restrict__ bbase,
                                                int* __restrict__ rowptr,
                                                float* __restrict__ dinv,
                                                int* __restrict__ srcs) {
  __shared__ int fill[NPB];
  __shared__ int nbase[NPB];
  __shared__ int sc[NPB];
  const int g = blockIdx.x, t = threadIdx.x;
  const int lo = g * NPB;
  const int b0 = bbase[g];
  const int n = bbase[g + 1] - b0;
  const unsigned long long* tp = temp + (size_t)g * CAP;
  if (t < NPB) fill[t] = 0;
  __syncthreads();
  for (int s = t; s < n; s += 256) {
    int cc = (int)(tp[s] >> 32);
    atomicAdd(&fill[cc & (NPB - 1)], 1);
  }
  __syncthreads();
  int v = 0;
  if (t < NPB) {
    v = fill[t];
    sc[t] = v;
  }
  __syncthreads();
  for (int off = 1; off < NPB; off <<= 1) {
    int x = 0;
    if (t < NPB && t >= off) x = sc[t - off];
    __syncthreads();
    if (t < NPB) sc[t] += x;
    __syncthreads();
  }
  if (t < NPB) {
    int excl = sc[t] - v;
    nbase[t] = b0 + excl;
    int node = lo + t;
    if (node < NN) {
      rowptr[node] = b0 + excl;
      dinv[node] = rsqrtf((float)(v + 1));  // +1 self loop
    }
    fill[t] = 0;
  }
  if (g == G - 1 && t == 0) rowptr[NN] = NE;
  __syncthreads();
  for (int s = t; s < n; s += 256) {
    unsigned long long p = tp[s];
    int cc = (int)(p >> 32);
    int rr = (int)(unsigned)(p & 0xffffffffull);
    int c = cc & (NPB - 1);
    int slot = atomicAdd(&fill[c], 1);
    srcs[nbase[c] + slot] = rr;
  }
}

// -------- weight convert (all 3): W fp32 [128][N] -> Wt fp16 [N][128] --------
__global__ __launch_bounds__(256) void k_wconvAll(const float* __restrict__ W1,
                                                  const float* __restrict__ W2,
                                                  const float* __restrict__ W3,
                                                  _Float16* __restrict__ w1h,
                                                  _Float16* __restrict__ w2h,
                                                  _Float16* __restrict__ w3h) {
  int i = blockIdx.x * 256 + threadIdx.x;
  if (i < 16384) {
    int k = i >> 7, c = i & 127;
    w1h[c * 128 + k] = (_Float16)W1[i];
  } else if (i < 32768) {
    int j = i - 16384;
    int k = j >> 7, c = j & 127;
    w2h[c * 128 + k] = (_Float16)W2[j];
  } else if (i < 40960) {
    int j = i - 32768;
    int k = j >> 6, c = j & 63;
    w3h[c * 128 + k] = (_Float16)W3[j];
  }
}

// ---------------- MFMA GEMM: Y = A @ W, fp16 in/out, fp32 accumulate --------
// Row M (== NN) of Y is written with ZEROS (dummy row for agg's unified tail).
template <int BN, bool F32IN>
__global__ __launch_bounds__(256, 2) void k_gemm_mfma(const void* __restrict__ Ain,
                                                      const _Float16* __restrict__ Wt_g,
                                                      const float* __restrict__ dinv,
                                                      _Float16* __restrict__ Y, int M) {
  constexpr int NB = BN / 16;
  __shared__ _Float16 Ah[128 * 128];  // 32 KB, swizzled rows of 256 B
  __shared__ _Float16 Wt[BN * 128];   // 32/16 KB, swizzled
  const int t = threadIdx.x;
  const int rbase = blockIdx.x * 128;

  for (int c = t; c < BN * 16; c += 256) {
    f16x8 v = *(const f16x8*)((const char*)Wt_g + c * 16);
    *(f16x8*)((char*)Wt + swz(c * 16)) = v;
  }
  if constexpr (F32IN) {
    const float* A = (const float*)Ain;
    for (int c = t; c < 2048; c += 256) {
      int r = c >> 4, kc = c & 15;
      int row = rbase + r;
      f16x8 h = {};
      if (row < M) {
        float dv = dinv[row];
        const float* p = A + (size_t)row * 128 + kc * 8;
        float4 u0 = *(const float4*)p;
        float4 u1 = *(const float4*)(p + 4);
        h[0] = (_Float16)(u0.x * dv);
        h[1] = (_Float16)(u0.y * dv);
        h[2] = (_Float16)(u0.z * dv);
        h[3] = (_Float16)(u0.w * dv);
        h[4] = (_Float16)(u1.x * dv);
        h[5] = (_Float16)(u1.y * dv);
        h[6] = (_Float16)(u1.z * dv);
        h[7] = (_Float16)(u1.w * dv);
      }
      *(f16x8*)((char*)Ah + swz(c * 16)) = h;
    }
  } else {
    const _Float16* A = (const _Float16*)Ain;
    for (int c = t; c < 2048; c += 256) {
      int r = c >> 4;
      int row = rbase + r;
      f16x8 h = {};
      if (row < M) h = *(const f16x8*)(A + (size_t)row * 128 + (c & 15) * 8);
      *(f16x8*)((char*)Ah + swz(c * 16)) = h;
    }
  }
  __syncthreads();

  const int wave = t >> 6, lane = t & 63;
  const int l16 = lane & 15, lk = lane >> 4;

  f32x4 acc[2][NB];
#pragma unroll
  for (int mm = 0; mm < 2; ++mm)
#pragma unroll
    for (int n = 0; n < NB; ++n) acc[mm][n] = (f32x4){0.f, 0.f, 0.f, 0.f};

#pragma unroll
  for (int ks = 0; ks < 4; ++ks) {
    const int kbyte = ks * 64 + lk * 16;
    f16x8 afr[2];
#pragma unroll
    for (int mm = 0; mm < 2; ++mm) {
      int row = wave * 32 + mm * 16 + l16;
      afr[mm] = *(const f16x8*)((const char*)Ah + swz(row * 256 + kbyte));
    }
#pragma unroll
    for (int n = 0; n < NB; ++n) {
      int wrow = n * 16 + l16;
      f16x8 wfr = *(const f16x8*)((const char*)Wt + swz(wrow * 256 + kbyte));
#pragma unroll
      for (int mm = 0; mm < 2; ++mm)
        acc[mm][n] = __builtin_amdgcn_mfma_f32_16x16x32_f16(wfr, afr[mm], acc[mm][n], 0, 0, 0);
    }
  }

#pragma unroll
  for (int mm = 0; mm < 2; ++mm) {
    int row = rbase + wave * 32 + mm * 16 + l16;
    if (row < M) {
      _Float16* yr = Y + (size_t)row * BN + lk * 4;
#pragma unroll
      for (int n = 0; n < NB; ++n) {
        f16x4 h = {(_Float16)acc[mm][n][0], (_Float16)acc[mm][n][1],
                   (_Float16)acc[mm][n][2], (_Float16)acc[mm][n][3]};
        *(f16x4*)(yr + n * 16) = h;
      }
    } else if (row == M) {  // zero dummy row for agg's unified tail
      _Float16* yr = Y + (size_t)row * BN + lk * 4;
      f16x4 z = {};
#pragma unroll
      for (int n = 0; n < NB; ++n) *(f16x4*)(yr + n * 16) = z;
    }
  }
}

// ---------------- aggregation (8 gathers in flight, zero-row padding) --------
// 32 edges per iteration: 8 independent row gathers issued before any
// accumulate. Pad lanes carry idx=NN (zeroed dummy row, L1-resident).
__global__ __launch_bounds__(256) void k_agg128h(const _Float16* __restrict__ Y,
                                                 const int* __restrict__ rowptr,
                                                 const int* __restrict__ srcs,
                                                 const float* __restrict__ dinv,
                                                 const float* __restrict__ bias,
                                                 _Float16* __restrict__ Out, int n) {
  const int wave = threadIdx.x >> 6;
  const int lane = threadIdx.x & 63;
  const int node = blockIdx.x * 4 + wave;
  if (node >= n) return;
  const int part = lane >> 4;  // which edge of the quad (0..3)
  const int q = lane & 15;     // element block: cols q*8..q*8+7
  const int jb = rowptr[node];
  const int je = rowptr[node + 1];

  float acc[8];
#pragma unroll
  for (int j = 0; j < 8; ++j) acc[j] = 0.f;
  {  // self loop
    half8 s = *(const half8*)(Y + (size_t)node * 128 + q * 8);
    if (part == 0) {
#pragma unroll
      for (int j = 0; j < 8; ++j) acc[j] = (float)s[j];
    }
  }

  for (int j0 = jb; j0 < je; j0 += 64) {
    const int m = min(64, je - j0);  // wave-uniform
    const int idx = (lane < m) ? srcs[j0 + lane] : NN;  // NN = zero row
    for (int eb = 0; eb < m; eb += 32) {  // uniform trip count
      const int e0 = eb + part;
      int s0 = __shfl(idx, e0);
      int s1 = __shfl(idx, e0 + 4);
      int s2 = __shfl(idx, e0 + 8);
      int s3 = __shfl(idx, e0 + 12);
      int s4 = __shfl(idx, e0 + 16);
      int s5 = __shfl(idx, e0 + 20);
      int s6 = __shfl(idx, e0 + 24);
      int s7 = __shfl(idx, e0 + 28);
      half8 v0 = *(const half8*)(Y + (size_t)s0 * 128 + q * 8);
      half8 v1 = *(const half8*)(Y + (size_t)s1 * 128 + q * 8);
      half8 v2 = *(const half8*)(Y + (size_t)s2 * 128 + q * 8);
      half8 v3 = *(const half8*)(Y + (size_t)s3 * 128 + q * 8);
      half8 v4 = *(const half8*)(Y + (size_t)s4 * 128 + q * 8);
      half8 v5 = *(const half8*)(Y + (size_t)s5 * 128 + q * 8);
      half8 v6 = *(const half8*)(Y + (size_t)s6 * 128 + q * 8);
      half8 v7 = *(const half8*)(Y + (size_t)s7 * 128 + q * 8);
      half8 sA = (v0 + v1) + (v2 + v3);  // per-16 fp16 trees (numerics as r7)
      half8 sB = (v4 + v5) + (v6 + v7);
#pragma unroll
      for (int j = 0; j < 8; ++j) acc[j] += (float)sA[j];
#pragma unroll
      for (int j = 0; j < 8; ++j) acc[j] += (float)sB[j];
    }
  }

#pragma unroll
  for (int j = 0; j < 8; ++j) {
    acc[j] += __shfl_xor(acc[j], 16);
    acc[j] += __shfl_xor(acc[j], 32);
  }

  if (part == 0) {
    const float dv = dinv[node];
    f16x8 h;
#pragma unroll
    for (int j = 0; j < 8; ++j) {
      float o = fmaf(acc[j], dv, bias[q * 8 + j]);
      o = fmaxf(o, 0.f);
      h[j] = (_Float16)(o * dv);  // pre-scale for next layer's GEMM
    }
    *(f16x8*)(Out + (size_t)node * 128 + q * 8) = h;
  }
}

// D=64 final layer: all 64 edges in one batch (8 gathers of 8-lane rows).
__global__ __launch_bounds__(256) void k_agg64h(const _Float16* __restrict__ Y,
                                                const int* __restrict__ rowptr,
                                                const int* __restrict__ srcs,
                                                const float* __restrict__ dinv,
                                                const float* __restrict__ bias,
                                                float* __restrict__ Out, int n) {
  const int wave = threadIdx.x >> 6;
  const int lane = threadIdx.x & 63;
  const int node = blockIdx.x * 4 + wave;
  if (node >= n) return;
  const int part = lane >> 3;  // which edge of the octet (0..7)
  const int q = lane & 7;      // element block: cols q*8..q*8+7
  const int jb = rowptr[node];
  const int je = rowptr[node + 1];

  float acc[8];
#pragma unroll
  for (int j = 0; j < 8; ++j) acc[j] = 0.f;
  {  // self loop
    half8 s = *(const half8*)(Y + (size_t)node * 64 + q * 8);
    if (part == 0) {
#pragma unroll
      for (int j = 0; j < 8; ++j) acc[j] = (float)s[j];
    }
  }

  for (int j0 = jb; j0 < je; j0 += 64) {
    const int m = min(64, je - j0);  // wave-uniform
    const int idx = (lane < m) ? srcs[j0 + lane] : NN;  // NN = zero row
    // all 64 edge-slots in one batch: 8 gathers in flight
    const int e0 = part;
    int s0 = __shfl(idx, e0);
    int s1 = __shfl(idx, e0 + 8);
    int s2 = __shfl(idx, e0 + 16);
    int s3 = __shfl(idx, e0 + 24);
    int s4 = __shfl(idx, e0 + 32);
    int s5 = __shfl(idx, e0 + 40);
    int s6 = __shfl(idx, e0 + 48);
    int s7 = __shfl(idx, e0 + 56);
    half8 v0 = *(const half8*)(Y + (size_t)s0 * 64 + q * 8);
    half8 v1 = *(const half8*)(Y + (size_t)s1 * 64 + q * 8);
    half8 v2 = *(const half8*)(Y + (size_t)s2 * 64 + q * 8);
    half8 v3 = *(const half8*)(Y + (size_t)s3 * 64 + q * 8);
    half8 v4 = *(const half8*)(Y + (size_t)s4 * 64 + q * 8);
    half8 v5 = *(const half8*)(Y + (size_t)s5 * 64 + q * 8);
    half8 v6 = *(const half8*)(Y + (size_t)s6 * 64 + q * 8);
    half8 v7 = *(const half8*)(Y + (size_t)s7 * 64 + q * 8);
    half8 sA = (v0 + v1) + (v2 + v3);
    half8 sB = (v4 + v5) + (v6 + v7);
#pragma unroll
    for (int j = 0; j < 8; ++j) acc[j] += (float)sA[j];
#pragma unroll
    for (int j = 0; j < 8; ++j) acc[j] += (float)sB[j];
  }

#pragma unroll
  for (int j = 0; j < 8; ++j) {
    acc[j] += __shfl_xor(acc[j], 8);
    acc[j] += __shfl_xor(acc[j], 16);
    acc[j] += __shfl_xor(acc[j], 32);
  }

  if (part == 0) {
    const float dv = dinv[node];
    float o[8];
#pragma unroll
    for (int j = 0; j < 8; ++j) o[j] = fmaf(acc[j], dv, bias[q * 8 + j]);
    float* orow = Out + (size_t)node * 64 + q * 8;
    *(float4*)(orow) = make_float4(o[0], o[1], o[2], o[3]);
    *(float4*)(orow + 4) = make_float4(o[4], o[5], o[6], o[7]);
  }
}

// ---------------- launch ----------------

extern "C" void kernel_launch(void* const* d_in, const int* in_sizes, int n_in,
                              void* d_out, int out_size, void* d_ws, size_t ws_size,
                              hipStream_t stream) {
  const float* x = (const float*)d_in[0];
  const int* ei = (const int*)d_in[1];
  const float* W1 = (const float*)d_in[2];
  const float* b1 = (const float*)d_in[3];
  const float* W2 = (const float*)d_in[4];
  const float* b2 = (const float*)d_in[5];
  const float* W3 = (const float*)d_in[6];
  const float* b3 = (const float*)d_in[7];
  float* out = (float*)d_out;

  const int* erow = ei;       // edge_index[0] = sources
  const int* ecol = ei + NE;  // edge_index[1] = targets

  char* w = (char*)d_ws;
  auto alloc = [&](size_t b) {
    char* p = w;
    w += (b + 255) & ~(size_t)255;
    return (void*)p;
  };
  float* dinv = (float*)alloc((size_t)NN * 4);
  int* rowptr = (int*)alloc((size_t)(NN + 1) * 4);
  int* cursor = (int*)alloc((size_t)G * 4);
  int* bbase = (int*)alloc((size_t)(G + 1) * 4);
  int* srcs = (int*)alloc((size_t)NE * 4);
  _Float16* w1h = (_Float16*)alloc((size_t)128 * 128 * 2);
  _Float16* w2h = (_Float16*)alloc((size_t)128 * 128 * 2);
  _Float16* w3h = (_Float16*)alloc((size_t)128 * 64 * 2);
  _Float16* ybuf = (_Float16*)alloc((size_t)(NN + 1) * 128 * 2);  // +1 zero row
  _Float16* hbuf = (_Float16*)alloc((size_t)(NN + 1) * 128 * 2);
  // temp edge pairs (25.02 MB) alias ybuf (25.6 MB, dead until first GEMM)
  unsigned long long* temp = (unsigned long long*)ybuf;

  // preprocessing: padded bucketed counting sort -> rowptr, srcs, dinv
  k_zero<<<(G + 255) / 256, 256, 0, stream>>>(cursor, G);
  k_bucketP<<<NCH, 256, 0, stream>>>(erow, ecol, cursor, temp);
  k_bscan<<<1, 256, 0, stream>>>(cursor, bbase);
  k_groupP<<<G, 256, 0, stream>>>(temp, bbase, rowptr, dinv, srcs);
  k_wconvAll<<<160, 256, 0, stream>>>(W1, W2, W3, w1h, w2h, w3h);

  const int nbG = (NN + 127) / 128;  // 782 (covers dummy row NN)
  const int nbA = (NN + 3) / 4;      // 25000

  // Layer 1: y1 = (dinv*x) @ W1  -> agg -> hbuf (fp16 pre-scaled)
  k_gemm_mfma<128, true><<<nbG, 256, 0, stream>>>(x, w1h, dinv, ybuf, NN);
  k_agg128h<<<nbA, 256, 0, stream>>>(ybuf, rowptr, srcs, dinv, b1, hbuf, NN);
  // Layer 2
  k_gemm_mfma<128, false><<<nbG, 256, 0, stream>>>(hbuf, w2h, dinv, ybuf, NN);
  k_agg128h<<<nbA, 256, 0, stream>>>(ybuf, rowptr, srcs, dinv, b2, hbuf, NN);
  // Layer 3: fp32 output
  k_gemm_mfma<64, false><<<nbG, 256, 0, stream>>>(hbuf, w3h, dinv, ybuf, NN);
  k_agg64h<<<nbA, 256, 0, stream>>>(ybuf, rowptr, srcs, dinv, b3, out, NN);
}

// Round 9
// 258.670 us; speedup vs baseline: 1.0791x; 1.0791x over previous
//
#include <hip/hip_runtime.h>

#define NN 100000
#define NE 1600000
constexpr int KDIM = 128;
constexpr int NPB = 128;                  // nodes per bucket (col>>7)
constexpr int G = (NN + NPB - 1) / NPB;   // 782 buckets
constexpr int CH = 8192;                  // edges per chunk
constexpr int NCH = (NE + CH - 1) / CH;   // 196 chunks
constexpr int CAP = 4000;                 // padded bucket capacity (mean 2046, sigma 45)

typedef unsigned int u32;
typedef _Float16 f16x4 __attribute__((ext_vector_type(4)));
typedef _Float16 f16x8 __attribute__((ext_vector_type(8)));
typedef float f32x4 __attribute__((ext_vector_type(4)));
using half8 = f16x8;

// LDS XOR swizzle for 256B-row-stride b128 access: spreads bank slots.
// Involution: swz(swz(x)) == x.
__device__ __forceinline__ int swz(int byte) {
  return byte ^ (((byte >> 8) & 7) << 4);
}

// async global->LDS 16B: wave-uniform LDS base + lane*16 (rule: per-lane GLOBAL addr ok)
__device__ __forceinline__ void gload16(const void* g, void* l) {
  __builtin_amdgcn_global_load_lds(
      (const __attribute__((address_space(1))) u32*)g,
      (__attribute__((address_space(3))) u32*)l, 16, 0, 0);
}

// ---------------- preprocessing: bucketed counting sort (padded) -------------

__global__ __launch_bounds__(256) void k_zero(int* p, int n) {
  int i = blockIdx.x * 256 + threadIdx.x;
  if (i < n) p[i] = 0;
}

// bin edges into padded bucket regions: LDS hist + bulk reservation + append.
// packed u32: (col&127)<<17 | row   (row < 2^17)
__global__ __launch_bounds__(256) void k_bucketP(const int* __restrict__ row,
                                                 const int* __restrict__ col,
                                                 int* __restrict__ cursor,
                                                 u32* __restrict__ temp) {
  __shared__ int h[G];
  for (int i = threadIdx.x; i < G; i += 256) h[i] = 0;
  __syncthreads();
  const int base = blockIdx.x * CH;
  const int m = min(CH, NE - base);
  for (int i = threadIdx.x; i < m; i += 256) atomicAdd(&h[col[base + i] >> 7], 1);
  __syncthreads();
  for (int i = threadIdx.x; i < G; i += 256) {
    int c = h[i];
    if (c) h[i] = atomicAdd(&cursor[i], c);  // h[i] becomes this WG's local base
  }
  __syncthreads();
  for (int i = threadIdx.x; i < m; i += 256) {
    int cc = col[base + i];
    int rr = row[base + i];
    int slot = atomicAdd(&h[cc >> 7], 1);
    temp[(size_t)(cc >> 7) * CAP + slot] = ((u32)(cc & 127) << 17) | (u32)rr;
  }
}

// block 0: exclusive scan of bucket counts -> bbase[0..G]
// blocks 1..160: weight convert W fp32 [128][N] -> Wt fp16 [N][128]
__global__ __launch_bounds__(256) void k_scan_wconv(const int* __restrict__ cnt,
                                                    int* __restrict__ bbase,
                                                    const float* __restrict__ W1,
                                                    const float* __restrict__ W2,
                                                    const float* __restrict__ W3,
                                                    _Float16* __restrict__ w1h,
                                                    _Float16* __restrict__ w2h,
                                                    _Float16* __restrict__ w3h) {
  const int t = threadIdx.x;
  if (blockIdx.x == 0) {
    __shared__ int sd[256];
    int v[4];
    int s = 0;
#pragma unroll
    for (int j = 0; j < 4; ++j) {
      int idx = t * 4 + j;
      v[j] = (idx < G) ? cnt[idx] : 0;
      s += v[j];
    }
    sd[t] = s;
    __syncthreads();
    for (int off = 1; off < 256; off <<= 1) {
      int x = (t >= off) ? sd[t - off] : 0;
      __syncthreads();
      sd[t] += x;
      __syncthreads();
    }
    int run = sd[t] - s;  // exclusive prefix
#pragma unroll
    for (int j = 0; j < 4; ++j) {
      int idx = t * 4 + j;
      if (idx < G) bbase[idx] = run;
      run += v[j];
    }
    if (t == 255) bbase[G] = run;  // == NE
  } else {
    int i = (blockIdx.x - 1) * 256 + t;
    if (i < 16384) {
      int k = i >> 7, c = i & 127;
      w1h[c * 128 + k] = (_Float16)W1[i];
    } else if (i < 32768) {
      int j = i - 16384;
      int k = j >> 7, c = j & 127;
      w2h[c * 128 + k] = (_Float16)W2[j];
    } else if (i < 40960) {
      int j = i - 32768;
      int k = j >> 6, c = j & 63;
      w3h[c * 128 + k] = (_Float16)W3[j];
    }
  }
}

// per-bucket: LDS node hist -> scan -> rowptr/dinv, then group srcs (CSR)
__global__ __launch_bounds__(256) void k_groupP(const u32* __restrict__ temp,
                                                const int* __restrict__ bbase,
                                                int* __restrict__ rowptr,
                                                float* __restrict__ dinv,
                                                int* __restrict__ srcs) {
  __shared__ int fill[NPB];
  __shared__ int nbase[NPB];
  __shared__ int sc[NPB];
  const int g = blockIdx.x, t = threadIdx.x;
  const int lo = g * NPB;
  const int b0 = bbase[g];
  const int n = bbase[g + 1] - b0;
  const u32* tp = temp + (size_t)g * CAP;
  if (t < NPB) fill[t] = 0;
  __syncthreads();
  for (int s = t; s < n; s += 256) atomicAdd(&fill[tp[s] >> 17], 1);
  __syncthreads();
  int v = 0;
  if (t < NPB) {
    v = fill[t];
    sc[t] = v;
  }
  __syncthreads();
  for (int off = 1; off < NPB; off <<= 1) {
    int x = 0;
    if (t < NPB && t >= off) x = sc[t - off];
    __syncthreads();
    if (t < NPB) sc[t] += x;
    __syncthreads();
  }
  if (t < NPB) {
    int excl = sc[t] - v;
    nbase[t] = b0 + excl;
    int node = lo + t;
    if (node < NN) {
      rowptr[node] = b0 + excl;
      dinv[node] = rsqrtf((float)(v + 1));  // +1 self loop
    }
    fill[t] = 0;
  }
  if (g == G - 1 && t == 0) rowptr[NN] = NE;
  __syncthreads();
  for (int s = t; s < n; s += 256) {
    u32 p = tp[s];
    int c = p >> 17;
    int slot = atomicAdd(&fill[c], 1);
    srcs[nbase[c] + slot] = (int)(p & 0x1FFFFu);
  }
}

// ---------------- MFMA GEMM: Y = A @ W, fp16 in/out, fp32 accumulate --------
// Row M (== NN) of Y is written with ZEROS (dummy row for agg's unified tail).
// Staging uses global_load_lds w16 with pre-swizzled per-lane global source
// (linear LDS dest; swz is an involution so src-perm == read-perm; rule 21).
template <int BN, bool F32IN>
__global__ __launch_bounds__(256, 2) void k_gemm_mfma(const void* __restrict__ Ain,
                                                      const _Float16* __restrict__ Wt_g,
                                                      const float* __restrict__ dinv,
                                                      _Float16* __restrict__ Y, int M) {
  constexpr int NB = BN / 16;
  __shared__ _Float16 Ah[128 * 128];  // 32 KB, swizzled rows of 256 B
  __shared__ _Float16 Wt[BN * 128];   // 32/16 KB, swizzled
  const int t = threadIdx.x;
  const int rbase = blockIdx.x * 128;
  const int wbase = (t & ~63) * 16;  // wave-uniform LDS byte base per iteration

  // stage Wt: async, pre-swizzled source
  {
    const char* Wg = (const char*)Wt_g;
    char* Wl = (char*)Wt;
#pragma unroll
    for (int c0 = 0; c0 < BN * 16; c0 += 256) {
      gload16(Wg + swz((c0 + t) * 16), Wl + c0 * 16 + wbase);
    }
  }
  // stage A
  if constexpr (F32IN) {
    const float* A = (const float*)Ain;
    for (int c = t; c < 2048; c += 256) {
      int r = c >> 4, kc = c & 15;
      int row = rbase + r;
      f16x8 h = {};
      if (row < M) {
        float dv = dinv[row];
        const float* p = A + (size_t)row * 128 + kc * 8;
        float4 u0 = *(const float4*)p;
        float4 u1 = *(const float4*)(p + 4);
        h[0] = (_Float16)(u0.x * dv);
        h[1] = (_Float16)(u0.y * dv);
        h[2] = (_Float16)(u0.z * dv);
        h[3] = (_Float16)(u0.w * dv);
        h[4] = (_Float16)(u1.x * dv);
        h[5] = (_Float16)(u1.y * dv);
        h[6] = (_Float16)(u1.z * dv);
        h[7] = (_Float16)(u1.w * dv);
      }
      *(f16x8*)((char*)Ah + swz(c * 16)) = h;
    }
  } else if (rbase + 128 <= M) {  // full tile: async staging
    const char* Ag = (const char*)Ain + (size_t)rbase * 256;
    char* Al = (char*)Ah;
#pragma unroll
    for (int c0 = 0; c0 < 2048; c0 += 256) {
      gload16(Ag + swz((c0 + t) * 16), Al + c0 * 16 + wbase);
    }
  } else {  // tail block: manual masked staging
    const _Float16* A = (const _Float16*)Ain;
    for (int c = t; c < 2048; c += 256) {
      int r = c >> 4;
      int row = rbase + r;
      f16x8 h = {};
      if (row < M) h = *(const f16x8*)(A + (size_t)row * 128 + (c & 15) * 8);
      *(f16x8*)((char*)Ah + swz(c * 16)) = h;
    }
  }
  __syncthreads();  // drains vmcnt (incl. global_load_lds) + lgkm

  const int wave = t >> 6, lane = t & 63;
  const int l16 = lane & 15, lk = lane >> 4;

  f32x4 acc[2][NB];
#pragma unroll
  for (int mm = 0; mm < 2; ++mm)
#pragma unroll
    for (int n = 0; n < NB; ++n) acc[mm][n] = (f32x4){0.f, 0.f, 0.f, 0.f};

#pragma unroll
  for (int ks = 0; ks < 4; ++ks) {
    const int kbyte = ks * 64 + lk * 16;
    f16x8 afr[2];
#pragma unroll
    for (int mm = 0; mm < 2; ++mm) {
      int row = wave * 32 + mm * 16 + l16;
      afr[mm] = *(const f16x8*)((const char*)Ah + swz(row * 256 + kbyte));
    }
#pragma unroll
    for (int n = 0; n < NB; ++n) {
      int wrow = n * 16 + l16;
      f16x8 wfr = *(const f16x8*)((const char*)Wt + swz(wrow * 256 + kbyte));
#pragma unroll
      for (int mm = 0; mm < 2; ++mm)
        acc[mm][n] = __builtin_amdgcn_mfma_f32_16x16x32_f16(wfr, afr[mm], acc[mm][n], 0, 0, 0);
    }
  }

#pragma unroll
  for (int mm = 0; mm < 2; ++mm) {
    int row = rbase + wave * 32 + mm * 16 + l16;
    if (row < M) {
      _Float16* yr = Y + (size_t)row * BN + lk * 4;
#pragma unroll
      for (int n = 0; n < NB; ++n) {
        f16x4 h = {(_Float16)acc[mm][n][0], (_Float16)acc[mm][n][1],
                   (_Float16)acc[mm][n][2], (_Float16)acc[mm][n][3]};
        *(f16x4*)(yr + n * 16) = h;
      }
    } else if (row == M) {  // zero dummy row for agg's unified tail
      _Float16* yr = Y + (size_t)row * BN + lk * 4;
      f16x4 z = {};
#pragma unroll
      for (int n = 0; n < NB; ++n) *(f16x4*)(yr + n * 16) = z;
    }
  }
}

// ---------------- aggregation (8 gathers in flight, zero-row padding) --------
__global__ __launch_bounds__(256) void k_agg128h(const _Float16* __restrict__ Y,
                                                 const int* __restrict__ rowptr,
                                                 const int* __restrict__ srcs,
                                                 const float* __restrict__ dinv,
                                                 const float* __restrict__ bias,
                                                 _Float16* __restrict__ Out, int n) {
  const int wave = threadIdx.x >> 6;
  const int lane = threadIdx.x & 63;
  const int node = blockIdx.x * 4 + wave;
  if (node >= n) return;
  const int part = lane >> 4;  // which edge of the quad (0..3)
  const int q = lane & 15;     // element block: cols q*8..q*8+7
  const int jb = rowptr[node];
  const int je = rowptr[node + 1];

  float acc[8];
#pragma unroll
  for (int j = 0; j < 8; ++j) acc[j] = 0.f;
  if (part == 0) {  // self loop
    half8 s = *(const half8*)(Y + (size_t)node * 128 + q * 8);
#pragma unroll
    for (int j = 0; j < 8; ++j) acc[j] = (float)s[j];
  }

  for (int j0 = jb; j0 < je; j0 += 64) {
    const int m = min(64, je - j0);  // wave-uniform
    const int idx = (lane < m) ? srcs[j0 + lane] : NN;  // NN = zero row
    for (int eb = 0; eb < m; eb += 32) {  // uniform trip count
      const int e0 = eb + part;
      int s0 = __shfl(idx, e0);
      int s1 = __shfl(idx, e0 + 4);
      int s2 = __shfl(idx, e0 + 8);
      int s3 = __shfl(idx, e0 + 12);
      int s4 = __shfl(idx, e0 + 16);
      int s5 = __shfl(idx, e0 + 20);
      int s6 = __shfl(idx, e0 + 24);
      int s7 = __shfl(idx, e0 + 28);
      half8 v0 = *(const half8*)(Y + (size_t)s0 * 128 + q * 8);
      half8 v1 = *(const half8*)(Y + (size_t)s1 * 128 + q * 8);
      half8 v2 = *(const half8*)(Y + (size_t)s2 * 128 + q * 8);
      half8 v3 = *(const half8*)(Y + (size_t)s3 * 128 + q * 8);
      half8 v4 = *(const half8*)(Y + (size_t)s4 * 128 + q * 8);
      half8 v5 = *(const half8*)(Y + (size_t)s5 * 128 + q * 8);
      half8 v6 = *(const half8*)(Y + (size_t)s6 * 128 + q * 8);
      half8 v7 = *(const half8*)(Y + (size_t)s7 * 128 + q * 8);
      half8 sA = (v0 + v1) + (v2 + v3);  // per-16 fp16 trees
      half8 sB = (v4 + v5) + (v6 + v7);
#pragma unroll
      for (int j = 0; j < 8; ++j) acc[j] += (float)sA[j];
#pragma unroll
      for (int j = 0; j < 8; ++j) acc[j] += (float)sB[j];
    }
  }

#pragma unroll
  for (int j = 0; j < 8; ++j) {
    acc[j] += __shfl_xor(acc[j], 16);
    acc[j] += __shfl_xor(acc[j], 32);
  }

  if (part == 0) {
    const float dv = dinv[node];
    f16x8 h;
#pragma unroll
    for (int j = 0; j < 8; ++j) {
      float o = fmaf(acc[j], dv, bias[q * 8 + j]);
      o = fmaxf(o, 0.f);
      h[j] = (_Float16)(o * dv);  // pre-scale for next layer's GEMM
    }
    *(f16x8*)(Out + (size_t)node * 128 + q * 8) = h;
  }
}

// D=64 final layer: all 64 edges in one batch (8 gathers of 8-lane rows).
__global__ __launch_bounds__(256) void k_agg64h(const _Float16* __restrict__ Y,
                                                const int* __restrict__ rowptr,
                                                const int* __restrict__ srcs,
                                                const float* __restrict__ dinv,
                                                const float* __restrict__ bias,
                                                float* __restrict__ Out, int n) {
  const int wave = threadIdx.x >> 6;
  const int lane = threadIdx.x & 63;
  const int node = blockIdx.x * 4 + wave;
  if (node >= n) return;
  const int part = lane >> 3;  // which edge of the octet (0..7)
  const int q = lane & 7;      // element block: cols q*8..q*8+7
  const int jb = rowptr[node];
  const int je = rowptr[node + 1];

  float acc[8];
#pragma unroll
  for (int j = 0; j < 8; ++j) acc[j] = 0.f;
  if (part == 0) {  // self loop
    half8 s = *(const half8*)(Y + (size_t)node * 64 + q * 8);
#pragma unroll
    for (int j = 0; j < 8; ++j) acc[j] = (float)s[j];
  }

  for (int j0 = jb; j0 < je; j0 += 64) {
    const int m = min(64, je - j0);  // wave-uniform
    const int idx = (lane < m) ? srcs[j0 + lane] : NN;  // NN = zero row
    const int e0 = part;
    int s0 = __shfl(idx, e0);
    int s1 = __shfl(idx, e0 + 8);
    int s2 = __shfl(idx, e0 + 16);
    int s3 = __shfl(idx, e0 + 24);
    int s4 = __shfl(idx, e0 + 32);
    int s5 = __shfl(idx, e0 + 40);
    int s6 = __shfl(idx, e0 + 48);
    int s7 = __shfl(idx, e0 + 56);
    half8 v0 = *(const half8*)(Y + (size_t)s0 * 64 + q * 8);
    half8 v1 = *(const half8*)(Y + (size_t)s1 * 64 + q * 8);
    half8 v2 = *(const half8*)(Y + (size_t)s2 * 64 + q * 8);
    half8 v3 = *(const half8*)(Y + (size_t)s3 * 64 + q * 8);
    half8 v4 = *(const half8*)(Y + (size_t)s4 * 64 + q * 8);
    half8 v5 = *(const half8*)(Y + (size_t)s5 * 64 + q * 8);
    half8 v6 = *(const half8*)(Y + (size_t)s6 * 64 + q * 8);
    half8 v7 = *(const half8*)(Y + (size_t)s7 * 64 + q * 8);
    half8 sA = (v0 + v1) + (v2 + v3);
    half8 sB = (v4 + v5) + (v6 + v7);
#pragma unroll
    for (int j = 0; j < 8; ++j) acc[j] += (float)sA[j];
#pragma unroll
    for (int j = 0; j < 8; ++j) acc[j] += (float)sB[j];
  }

#pragma unroll
  for (int j = 0; j < 8; ++j) {
    acc[j] += __shfl_xor(acc[j], 8);
    acc[j] += __shfl_xor(acc[j], 16);
    acc[j] += __shfl_xor(acc[j], 32);
  }

  if (part == 0) {
    const float dv = dinv[node];
    float o[8];
#pragma unroll
    for (int j = 0; j < 8; ++j) o[j] = fmaf(acc[j], dv, bias[q * 8 + j]);
    float* orow = Out + (size_t)node * 64 + q * 8;
    *(float4*)(orow) = make_float4(o[0], o[1], o[2], o[3]);
    *(float4*)(orow + 4) = make_float4(o[4], o[5], o[6], o[7]);
  }
}

// ---------------- launch ----------------

extern "C" void kernel_launch(void* const* d_in, const int* in_sizes, int n_in,
                              void* d_out, int out_size, void* d_ws, size_t ws_size,
                              hipStream_t stream) {
  const float* x = (const float*)d_in[0];
  const int* ei = (const int*)d_in[1];
  const float* W1 = (const float*)d_in[2];
  const float* b1 = (const float*)d_in[3];
  const float* W2 = (const float*)d_in[4];
  const float* b2 = (const float*)d_in[5];
  const float* W3 = (const float*)d_in[6];
  const float* b3 = (const float*)d_in[7];
  float* out = (float*)d_out;

  const int* erow = ei;       // edge_index[0] = sources
  const int* ecol = ei + NE;  // edge_index[1] = targets

  char* w = (char*)d_ws;
  auto alloc = [&](size_t b) {
    char* p = w;
    w += (b + 255) & ~(size_t)255;
    return (void*)p;
  };
  float* dinv = (float*)alloc((size_t)NN * 4);
  int* rowptr = (int*)alloc((size_t)(NN + 1) * 4);
  int* cursor = (int*)alloc((size_t)G * 4);
  int* bbase = (int*)alloc((size_t)(G + 1) * 4);
  int* srcs = (int*)alloc((size_t)NE * 4);
  _Float16* w1h = (_Float16*)alloc((size_t)128 * 128 * 2);
  _Float16* w2h = (_Float16*)alloc((size_t)128 * 128 * 2);
  _Float16* w3h = (_Float16*)alloc((size_t)128 * 64 * 2);
  _Float16* ybuf = (_Float16*)alloc((size_t)(NN + 1) * 128 * 2);  // +1 zero row
  _Float16* hbuf = (_Float16*)alloc((size_t)(NN + 1) * 128 * 2);
  // temp packed u32 (12.5 MB) aliases ybuf (25.6 MB, dead until first GEMM)
  u32* temp = (u32*)ybuf;

  // preprocessing: padded bucketed counting sort -> rowptr, srcs, dinv
  k_zero<<<(G + 255) / 256, 256, 0, stream>>>(cursor, G);
  k_bucketP<<<NCH, 256, 0, stream>>>(erow, ecol, cursor, temp);
  k_scan_wconv<<<161, 256, 0, stream>>>(cursor, bbase, W1, W2, W3, w1h, w2h, w3h);
  k_groupP<<<G, 256, 0, stream>>>(temp, bbase, rowptr, dinv, srcs);

  const int nbG = (NN + 127) / 128;  // 782 (covers dummy row NN)
  const int nbA = (NN + 3) / 4;      // 25000

  // Layer 1: y1 = (dinv*x) @ W1  -> agg -> hbuf (fp16 pre-scaled)
  k_gemm_mfma<128, true><<<nbG, 256, 0, stream>>>(x, w1h, dinv, ybuf, NN);
  k_agg128h<<<nbA, 256, 0, stream>>>(ybuf, rowptr, srcs, dinv, b1, hbuf, NN);
  // Layer 2
  k_gemm_mfma<128, false><<<nbG, 256, 0, stream>>>(hbuf, w2h, dinv, ybuf, NN);
  k_agg128h<<<nbA, 256, 0, stream>>>(ybuf, rowptr, srcs, dinv, b2, hbuf, NN);
  // Layer 3: fp32 output
  k_gemm_mfma<64, false><<<nbG, 256, 0, stream>>>(hbuf, w3h, dinv, ybuf, NN);
  k_agg64h<<<nbA, 256, 0, stream>>>(ybuf, rowptr, srcs, dinv, b3, out, NN);
}